// Round 4
// baseline (574.415 us; speedup 1.0000x reference)
//
#include <hip/hip_runtime.h>
#include <hip/hip_bf16.h>

// ---------------------------------------------------------------------------
// SelfAttention: y = proj(attn(qkv(x)))   B=4 T=2048 C=1024 H=16 HD=64
// Inputs/outputs are FLOAT32 (per reference); pad_mask is int32.
// Internally: convert to bf16, MFMA 16x16x32 bf16, accumulate f32.
// ---------------------------------------------------------------------------

using short8  = __attribute__((ext_vector_type(8))) short;
using float4_ = __attribute__((ext_vector_type(4))) float;

#define Bb   4
#define Tt   2048
#define Cc   1024
#define Hh   16
#define HDd  64

__device__ __forceinline__ float bf2f(unsigned short u) {
    union { float f; unsigned int i; } x; x.i = ((unsigned int)u) << 16; return x.f;
}
__device__ __forceinline__ unsigned short f2bf(float f) {
    union { float f; unsigned int i; } x; x.f = f;
    unsigned int r = x.i + 0x7fff + ((x.i >> 16) & 1);
    return (unsigned short)(r >> 16);
}

// ---------------------------------------------------------------------------
// Transpose + convert: in f32 [R][Ccols] -> out bf16 [Ccols][R]
// ---------------------------------------------------------------------------
__global__ __launch_bounds__(256) void transpose_f32_bf16(
    const float* __restrict__ in, unsigned short* __restrict__ out,
    int R, int Ccols)
{
    __shared__ unsigned short tile[32][33];
    int c0 = blockIdx.x * 32, r0 = blockIdx.y * 32;
    int tx = threadIdx.x & 31, ty = threadIdx.x >> 5;   // ty 0..7
    for (int o = 0; o < 32; o += 8)
        tile[ty + o][tx] = f2bf(in[(size_t)(r0 + ty + o) * Ccols + c0 + tx]);
    __syncthreads();
    for (int o = 0; o < 32; o += 8)
        out[(size_t)(c0 + ty + o) * R + r0 + tx] = tile[tx][ty + o];
}

// ---------------------------------------------------------------------------
// GEMM: C = A[M][K](f32) * Bt[N][K](bf16)^T
// 64x64 block tile, BK=32, 4 waves each computing 32x32 via 2x2 MFMA 16x16x32.
// ---------------------------------------------------------------------------
#define BM  64
#define BN  64
#define BK  32
#define LDA 40   // padded LDS row stride (elems): 80B, 16B-aligned

__device__ __forceinline__ short8 ld_cvt8(const float* p) {
    float4_ f0 = *(const float4_*)p;
    float4_ f1 = *(const float4_*)(p + 4);
    short8 h;
    h[0] = (short)f2bf(f0[0]); h[1] = (short)f2bf(f0[1]);
    h[2] = (short)f2bf(f0[2]); h[3] = (short)f2bf(f0[3]);
    h[4] = (short)f2bf(f1[0]); h[5] = (short)f2bf(f1[1]);
    h[6] = (short)f2bf(f1[2]); h[7] = (short)f2bf(f1[3]);
    return h;
}

__global__ __launch_bounds__(256) void gemm_qkv(
    const float* __restrict__ A,            // x: [8192][1024] f32
    const unsigned short* __restrict__ Bt,  // w_attn^T: [3072][1024] bf16
    unsigned short* __restrict__ Q,         // [B][H][T][HD] bf16
    unsigned short* __restrict__ Ko,
    unsigned short* __restrict__ V)
{
    __shared__ unsigned short As[BM * LDA];
    __shared__ unsigned short Bs[BN * LDA];
    const int K = 1024;
    int m0 = blockIdx.x * BM;
    int n0 = blockIdx.y * BN;
    int tid  = threadIdx.x;
    int wave = tid >> 6, lane = tid & 63;
    int wm = (wave >> 1) * 32, wn = (wave & 1) * 32;
    int lr = lane & 15, lk = (lane >> 4) * 8;
    int sr = tid >> 2, sc = (tid & 3) * 8;

    float4_ acc[2][2] = {};
    for (int k0 = 0; k0 < K; k0 += BK) {
        *(short8*)&As[sr * LDA + sc] = ld_cvt8(&A[(size_t)(m0 + sr) * K + k0 + sc]);
        *(short8*)&Bs[sr * LDA + sc] = *(const short8*)&Bt[(size_t)(n0 + sr) * K + k0 + sc];
        __syncthreads();
        short8 a0 = *(short8*)&As[(wm +      lr) * LDA + lk];
        short8 a1 = *(short8*)&As[(wm + 16 + lr) * LDA + lk];
        short8 b0 = *(short8*)&Bs[(wn +      lr) * LDA + lk];
        short8 b1 = *(short8*)&Bs[(wn + 16 + lr) * LDA + lk];
        acc[0][0] = __builtin_amdgcn_mfma_f32_16x16x32_bf16(a0, b0, acc[0][0], 0, 0, 0);
        acc[0][1] = __builtin_amdgcn_mfma_f32_16x16x32_bf16(a0, b1, acc[0][1], 0, 0, 0);
        acc[1][0] = __builtin_amdgcn_mfma_f32_16x16x32_bf16(a1, b0, acc[1][0], 0, 0, 0);
        acc[1][1] = __builtin_amdgcn_mfma_f32_16x16x32_bf16(a1, b1, acc[1][1], 0, 0, 0);
        __syncthreads();
    }
    for (int i = 0; i < 2; i++)
        for (int j = 0; j < 2; j++) {
            int n = n0 + wn + 16 * j + lr;
            int which = n >> 10;
            int c = n & 1023;
            int h = c >> 6, d = c & 63;
            unsigned short* dst = (which == 0) ? Q : ((which == 1) ? Ko : V);
            for (int r = 0; r < 4; r++) {
                int m = m0 + wm + 16 * i + (lane >> 4) * 4 + r;
                int b = m >> 11, t = m & 2047;
                dst[(((size_t)(b * Hh + h) * Tt) + t) * HDd + d] = f2bf(acc[i][j][r]);
            }
        }
}

__global__ __launch_bounds__(256) void gemm_proj(
    const unsigned short* __restrict__ A,   // y: [8192][1024] bf16
    const unsigned short* __restrict__ Bt,  // w_proj^T: [1024][1024] bf16
    const float* __restrict__ bias,         // [1024] f32
    float* __restrict__ Out)                // [8192][1024] f32
{
    __shared__ unsigned short As[BM * LDA];
    __shared__ unsigned short Bs[BN * LDA];
    const int K = 1024;
    int m0 = blockIdx.x * BM;
    int n0 = blockIdx.y * BN;
    int tid  = threadIdx.x;
    int wave = tid >> 6, lane = tid & 63;
    int wm = (wave >> 1) * 32, wn = (wave & 1) * 32;
    int lr = lane & 15, lk = (lane >> 4) * 8;
    int sr = tid >> 2, sc = (tid & 3) * 8;

    float4_ acc[2][2] = {};
    for (int k0 = 0; k0 < K; k0 += BK) {
        *(short8*)&As[sr * LDA + sc] = *(const short8*)&A [(size_t)(m0 + sr) * K + k0 + sc];
        *(short8*)&Bs[sr * LDA + sc] = *(const short8*)&Bt[(size_t)(n0 + sr) * K + k0 + sc];
        __syncthreads();
        short8 a0 = *(short8*)&As[(wm +      lr) * LDA + lk];
        short8 a1 = *(short8*)&As[(wm + 16 + lr) * LDA + lk];
        short8 b0 = *(short8*)&Bs[(wn +      lr) * LDA + lk];
        short8 b1 = *(short8*)&Bs[(wn + 16 + lr) * LDA + lk];
        acc[0][0] = __builtin_amdgcn_mfma_f32_16x16x32_bf16(a0, b0, acc[0][0], 0, 0, 0);
        acc[0][1] = __builtin_amdgcn_mfma_f32_16x16x32_bf16(a0, b1, acc[0][1], 0, 0, 0);
        acc[1][0] = __builtin_amdgcn_mfma_f32_16x16x32_bf16(a1, b0, acc[1][0], 0, 0, 0);
        acc[1][1] = __builtin_amdgcn_mfma_f32_16x16x32_bf16(a1, b1, acc[1][1], 0, 0, 0);
        __syncthreads();
    }
    for (int i = 0; i < 2; i++)
        for (int j = 0; j < 2; j++) {
            int n = n0 + wn + 16 * j + lr;
            float bv = bias[n];
            for (int r = 0; r < 4; r++) {
                int m = m0 + wm + 16 * i + (lane >> 4) * 4 + r;
                Out[(size_t)m * 1024 + n] = acc[i][j][r] + bv;
            }
        }
}

// ---------------------------------------------------------------------------
// Flash attention (causal + key pad mask), PAIRED q-tiles for load balance.
// Block (qpair, bh) handles q-tiles qbA=qpair and qbB=31-qpair: every block
// does exactly 33 compute-iterations; shared K/V prefix staged once.
// Vt uses XOR key-block swizzle to kill transpose-store bank conflicts.
// ---------------------------------------------------------------------------
#define DPAD 72   // padded row stride (elems) = 144B

__device__ __forceinline__ float4_ bmfma(short8 a, short8 b, float4_ c) {
    return __builtin_amdgcn_mfma_f32_16x16x32_bf16(a, b, c, 0, 0, 0);
}

__device__ __forceinline__ void attn_tile(
    int k0, int q0, const int* __restrict__ padRow, int lr, int lg,
    const unsigned short* Kt, const unsigned short* Vt, unsigned short* Pw,
    short8 qf0, short8 qf1,
    float m_i[4], float l_i[4], float4_ o_acc[4])
{
    const float scale = 0.125f;   // 1/sqrt(64)
    float4_ s[4];
    #pragma unroll
    for (int nt = 0; nt < 4; nt++) {
        short8 kf0 = *(const short8*)&Kt[(nt * 16 + lr) * DPAD + lg * 8];
        short8 kf1 = *(const short8*)&Kt[(nt * 16 + lr) * DPAD + 32 + lg * 8];
        float4_ a = (float4_){0.f, 0.f, 0.f, 0.f};
        a = bmfma(qf0, kf0, a);
        a = bmfma(qf1, kf1, a);
        s[nt] = a;
    }
    #pragma unroll
    for (int nt = 0; nt < 4; nt++) {
        int key = k0 + nt * 16 + lr;
        bool keep_k = padRow[key] != 0;
        #pragma unroll
        for (int r = 0; r < 4; r++) {
            int qrow = q0 + lg * 4 + r;
            float sv = s[nt][r] * scale;
            if (!keep_k || key > qrow) sv = -1e30f;
            s[nt][r] = sv;
        }
    }
    float mn[4], alpha[4];
    #pragma unroll
    for (int r = 0; r < 4; r++) {
        float v = fmaxf(fmaxf(s[0][r], s[1][r]), fmaxf(s[2][r], s[3][r]));
        #pragma unroll
        for (int off = 1; off < 16; off <<= 1)
            v = fmaxf(v, __shfl_xor(v, off, 64));
        float m_new = fmaxf(m_i[r], v);
        alpha[r] = __expf(m_i[r] - m_new);
        mn[r] = m_new;
    }
    float rsum[4] = {0.f, 0.f, 0.f, 0.f};
    #pragma unroll
    for (int nt = 0; nt < 4; nt++)
        #pragma unroll
        for (int r = 0; r < 4; r++) {
            float p = __expf(s[nt][r] - mn[r]);
            s[nt][r] = p;
            rsum[r] += p;
        }
    #pragma unroll
    for (int r = 0; r < 4; r++) {
        float v = rsum[r];
        #pragma unroll
        for (int off = 1; off < 16; off <<= 1)
            v += __shfl_xor(v, off, 64);
        l_i[r] = l_i[r] * alpha[r] + v;
        m_i[r] = mn[r];
    }
    // P: C-layout regs -> wave-private LDS -> A-layout fragments
    #pragma unroll
    for (int nt = 0; nt < 4; nt++)
        #pragma unroll
        for (int r = 0; r < 4; r++)
            Pw[(lg * 4 + r) * DPAD + nt * 16 + lr] = f2bf(s[nt][r]);
    #pragma unroll
    for (int dt = 0; dt < 4; dt++)
        #pragma unroll
        for (int r = 0; r < 4; r++)
            o_acc[dt][r] *= alpha[r];
    short8 pf0 = *(const short8*)&Pw[lr * DPAD + lg * 8];
    short8 pf1 = *(const short8*)&Pw[lr * DPAD + 32 + lg * 8];
    #pragma unroll
    for (int dt = 0; dt < 4; dt++) {
        int d = dt * 16 + lr;
        short8 vf0 = *(const short8*)&Vt[d * DPAD + ((lg ^ (d >> 3)) << 3)];
        short8 vf1 = *(const short8*)&Vt[d * DPAD + (((lg + 4) ^ (d >> 3)) << 3)];
        o_acc[dt] = bmfma(pf0, vf0, o_acc[dt]);
        o_acc[dt] = bmfma(pf1, vf1, o_acc[dt]);
    }
}

__global__ __launch_bounds__(256, 4) void attn_fwd(
    const unsigned short* __restrict__ Q,   // [B][H][T][HD]
    const unsigned short* __restrict__ Kg,
    const unsigned short* __restrict__ Vg,
    const int* __restrict__ pad,            // [B][T]
    unsigned short* __restrict__ Y)         // [B][T][C]
{
    __shared__ unsigned short Kt[64 * DPAD];      // [key][d]
    __shared__ unsigned short Vt[64 * DPAD];      // [d][key-swizzled]
    __shared__ unsigned short Pl[4 * 16 * DPAD];  // per-wave [qrow][key]

    int qpair = blockIdx.x;         // 0..15
    int bh = blockIdx.y;            // 0..63
    int b  = bh >> 4, h = bh & 15;
    const size_t base = (size_t)bh * Tt * HDd;
    int tid  = threadIdx.x;
    int wave = tid >> 6, lane = tid & 63;
    int lr = lane & 15, lg = lane >> 4;
    unsigned short* Pw = &Pl[wave * 16 * DPAD];
    const int* padRow = pad + b * Tt;

    int qbA = qpair, qbB = 31 - qpair;
    int q0A = qbA * 64 + wave * 16;
    int q0B = qbB * 64 + wave * 16;

    short8 qfA0 = *(const short8*)&Q[base + (size_t)(q0A + lr) * HDd + lg * 8];
    short8 qfA1 = *(const short8*)&Q[base + (size_t)(q0A + lr) * HDd + 32 + lg * 8];
    short8 qfB0 = *(const short8*)&Q[base + (size_t)(q0B + lr) * HDd + lg * 8];
    short8 qfB1 = *(const short8*)&Q[base + (size_t)(q0B + lr) * HDd + 32 + lg * 8];

    float mA[4], lA[4], mB[4], lB[4];
    float4_ oA[4], oB[4];
    #pragma unroll
    for (int r = 0; r < 4; r++) { mA[r] = -1e30f; lA[r] = 0.f; mB[r] = -1e30f; lB[r] = 0.f; }
    #pragma unroll
    for (int dt = 0; dt < 4; dt++) {
        oA[dt] = (float4_){0.f, 0.f, 0.f, 0.f};
        oB[dt] = (float4_){0.f, 0.f, 0.f, 0.f};
    }

    for (int kt = 0; kt <= qbB; kt++) {
        int k0 = kt * 64;
        // stage K (as-is) and V (transposed, XOR key-block swizzled)
        {
            int r = tid >> 2, cbase = (tid & 3) * 8;
            #pragma unroll
            for (int half = 0; half < 2; half++) {
                int c = cbase + half * 32;
                *(short8*)&Kt[r * DPAD + c] =
                    *(const short8*)&Kg[base + (size_t)(k0 + r) * HDd + c];
                alignas(16) unsigned short tmp[8];
                *(short8*)tmp = *(const short8*)&Vg[base + (size_t)(k0 + r) * HDd + c];
                #pragma unroll
                for (int j = 0; j < 8; j++) {
                    int d = c + j;
                    Vt[d * DPAD + ((((r >> 3) ^ (d >> 3)) << 3) | (r & 7))] = tmp[j];
                }
            }
        }
        __syncthreads();

        attn_tile(k0, q0B, padRow, lr, lg, Kt, Vt, Pw, qfB0, qfB1, mB, lB, oB);
        if (kt <= qbA)
            attn_tile(k0, q0A, padRow, lr, lg, Kt, Vt, Pw, qfA0, qfA1, mA, lA, oA);

        __syncthreads();
    }

    // epilogue: Y[b][t][h*64+d] = O / l  (bf16)
    #pragma unroll
    for (int dt = 0; dt < 4; dt++)
        #pragma unroll
        for (int r = 0; r < 4; r++) {
            int qrowA = q0A + lg * 4 + r;
            int qrowB = q0B + lg * 4 + r;
            Y[((size_t)b * Tt + qrowA) * Cc + h * HDd + dt * 16 + lr] = f2bf(oA[dt][r] / lA[r]);
            Y[((size_t)b * Tt + qrowB) * Cc + h * HDd + dt * 16 + lr] = f2bf(oB[dt][r] / lB[r]);
        }
}

// ---------------------------------------------------------------------------
extern "C" void kernel_launch(void* const* d_in, const int* in_sizes, int n_in,
                              void* d_out, int out_size, void* d_ws, size_t ws_size,
                              hipStream_t stream)
{
    const float* x      = (const float*)d_in[0];
    const int*   pad    = (const int*)d_in[1];
    const float* w_attn = (const float*)d_in[2];
    const float* w_proj = (const float*)d_in[3];
    const float* b_proj = (const float*)d_in[4];
    float*       out    = (float*)d_out;

    // workspace carve-up (bf16 elems)
    unsigned short* Wta = (unsigned short*)d_ws;            // 3072*1024
    unsigned short* Wtp = Wta + (size_t)3072 * 1024;        // 1024*1024
    unsigned short* Qb  = Wtp + (size_t)1024 * 1024;
    unsigned short* Kb  = Qb + (size_t)Bb * Hh * Tt * HDd;
    unsigned short* Vb  = Kb + (size_t)Bb * Hh * Tt * HDd;
    unsigned short* Yb  = Vb + (size_t)Bb * Hh * Tt * HDd;

    // 1) transpose+convert weights to bf16 [N][K]
    transpose_f32_bf16<<<dim3(3072 / 32, 1024 / 32), 256, 0, stream>>>(w_attn, Wta, 1024, 3072);
    transpose_f32_bf16<<<dim3(1024 / 32, 1024 / 32), 256, 0, stream>>>(w_proj, Wtp, 1024, 1024);
    // 2) qkv = x @ w_attn, scattered to head-major Q/K/V (bf16)
    gemm_qkv<<<dim3(8192 / BM, 3072 / BN), 256, 0, stream>>>(x, Wta, Qb, Kb, Vb);
    // 3) flash attention, paired q-tiles
    attn_fwd<<<dim3(16, Bb * Hh), 256, 0, stream>>>(Qb, Kb, Vb, pad, Yb);
    // 4) out = y @ w_proj + b_proj (f32 out)
    gemm_proj<<<dim3(8192 / BM, 1024 / BN), 256, 0, stream>>>(Yb, Wtp, b_proj, out);
}

// Round 5
// 389.119 us; speedup vs baseline: 1.4762x; 1.4762x over previous
//
#include <hip/hip_runtime.h>
#include <hip/hip_bf16.h>

// ---------------------------------------------------------------------------
// SelfAttention: y = proj(attn(qkv(x)))   B=4 T=2048 C=1024 H=16 HD=64
// Inputs/outputs are FLOAT32 (per reference); pad_mask is int32.
// Internally: convert to bf16, MFMA 16x16x32 bf16, accumulate f32.
// ---------------------------------------------------------------------------

using short8  = __attribute__((ext_vector_type(8))) short;
using float4_ = __attribute__((ext_vector_type(4))) float;

#define Bb   4
#define Tt   2048
#define Cc   1024
#define Hh   16
#define HDd  64

__device__ __forceinline__ float bf2f(unsigned short u) {
    union { float f; unsigned int i; } x; x.i = ((unsigned int)u) << 16; return x.f;
}
__device__ __forceinline__ unsigned short f2bf(float f) {
    union { float f; unsigned int i; } x; x.f = f;
    unsigned int r = x.i + 0x7fff + ((x.i >> 16) & 1);
    return (unsigned short)(r >> 16);
}

// ---------------------------------------------------------------------------
// Transpose + convert: in f32 [R][Ccols] -> out bf16 [Ccols][R]
// ---------------------------------------------------------------------------
__global__ __launch_bounds__(256) void transpose_f32_bf16(
    const float* __restrict__ in, unsigned short* __restrict__ out,
    int R, int Ccols)
{
    __shared__ unsigned short tile[32][33];
    int c0 = blockIdx.x * 32, r0 = blockIdx.y * 32;
    int tx = threadIdx.x & 31, ty = threadIdx.x >> 5;   // ty 0..7
    for (int o = 0; o < 32; o += 8)
        tile[ty + o][tx] = f2bf(in[(size_t)(r0 + ty + o) * Ccols + c0 + tx]);
    __syncthreads();
    for (int o = 0; o < 32; o += 8)
        out[(size_t)(c0 + ty + o) * R + r0 + tx] = tile[tx][ty + o];
}

// ---------------------------------------------------------------------------
// GEMM: C = A[M][K](f32) * Bt[N][K](bf16)^T
// 64x64 block tile, BK=32, 4 waves each computing 32x32 via 2x2 MFMA 16x16x32.
// ---------------------------------------------------------------------------
#define BM  64
#define BN  64
#define BK  32
#define LDA 40   // padded LDS row stride (elems): 80B, 16B-aligned

__device__ __forceinline__ short8 ld_cvt8(const float* p) {
    float4_ f0 = *(const float4_*)p;
    float4_ f1 = *(const float4_*)(p + 4);
    short8 h;
    h[0] = (short)f2bf(f0[0]); h[1] = (short)f2bf(f0[1]);
    h[2] = (short)f2bf(f0[2]); h[3] = (short)f2bf(f0[3]);
    h[4] = (short)f2bf(f1[0]); h[5] = (short)f2bf(f1[1]);
    h[6] = (short)f2bf(f1[2]); h[7] = (short)f2bf(f1[3]);
    return h;
}

__global__ __launch_bounds__(256) void gemm_qkv(
    const float* __restrict__ A,            // x: [8192][1024] f32
    const unsigned short* __restrict__ Bt,  // w_attn^T: [3072][1024] bf16
    unsigned short* __restrict__ Q,         // [B][H][T][HD] bf16 (pre-scaled by 1/8)
    unsigned short* __restrict__ Ko,
    unsigned short* __restrict__ V)
{
    __shared__ unsigned short As[BM * LDA];
    __shared__ unsigned short Bs[BN * LDA];
    const int K = 1024;
    int m0 = blockIdx.x * BM;
    int n0 = blockIdx.y * BN;
    int tid  = threadIdx.x;
    int wave = tid >> 6, lane = tid & 63;
    int wm = (wave >> 1) * 32, wn = (wave & 1) * 32;
    int lr = lane & 15, lk = (lane >> 4) * 8;
    int sr = tid >> 2, sc = (tid & 3) * 8;

    float4_ acc[2][2] = {};
    for (int k0 = 0; k0 < K; k0 += BK) {
        *(short8*)&As[sr * LDA + sc] = ld_cvt8(&A[(size_t)(m0 + sr) * K + k0 + sc]);
        *(short8*)&Bs[sr * LDA + sc] = *(const short8*)&Bt[(size_t)(n0 + sr) * K + k0 + sc];
        __syncthreads();
        short8 a0 = *(short8*)&As[(wm +      lr) * LDA + lk];
        short8 a1 = *(short8*)&As[(wm + 16 + lr) * LDA + lk];
        short8 b0 = *(short8*)&Bs[(wn +      lr) * LDA + lk];
        short8 b1 = *(short8*)&Bs[(wn + 16 + lr) * LDA + lk];
        acc[0][0] = __builtin_amdgcn_mfma_f32_16x16x32_bf16(a0, b0, acc[0][0], 0, 0, 0);
        acc[0][1] = __builtin_amdgcn_mfma_f32_16x16x32_bf16(a0, b1, acc[0][1], 0, 0, 0);
        acc[1][0] = __builtin_amdgcn_mfma_f32_16x16x32_bf16(a1, b0, acc[1][0], 0, 0, 0);
        acc[1][1] = __builtin_amdgcn_mfma_f32_16x16x32_bf16(a1, b1, acc[1][1], 0, 0, 0);
        __syncthreads();
    }
    for (int i = 0; i < 2; i++)
        for (int j = 0; j < 2; j++) {
            int n = n0 + wn + 16 * j + lr;
            int which = n >> 10;
            int c = n & 1023;
            int h = c >> 6, d = c & 63;
            unsigned short* dst = (which == 0) ? Q : ((which == 1) ? Ko : V);
            float sc2 = (which == 0) ? 0.125f : 1.0f;   // fold 1/sqrt(64) into Q
            for (int r = 0; r < 4; r++) {
                int m = m0 + wm + 16 * i + (lane >> 4) * 4 + r;
                int b = m >> 11, t = m & 2047;
                dst[(((size_t)(b * Hh + h) * Tt) + t) * HDd + d] = f2bf(acc[i][j][r] * sc2);
            }
        }
}

__global__ __launch_bounds__(256) void gemm_proj(
    const unsigned short* __restrict__ A,   // y: [8192][1024] bf16
    const unsigned short* __restrict__ Bt,  // w_proj^T: [1024][1024] bf16
    const float* __restrict__ bias,         // [1024] f32
    float* __restrict__ Out)                // [8192][1024] f32
{
    __shared__ unsigned short As[BM * LDA];
    __shared__ unsigned short Bs[BN * LDA];
    const int K = 1024;
    int m0 = blockIdx.x * BM;
    int n0 = blockIdx.y * BN;
    int tid  = threadIdx.x;
    int wave = tid >> 6, lane = tid & 63;
    int wm = (wave >> 1) * 32, wn = (wave & 1) * 32;
    int lr = lane & 15, lk = (lane >> 4) * 8;
    int sr = tid >> 2, sc = (tid & 3) * 8;

    float4_ acc[2][2] = {};
    for (int k0 = 0; k0 < K; k0 += BK) {
        *(short8*)&As[sr * LDA + sc] = *(const short8*)&A [(size_t)(m0 + sr) * K + k0 + sc];
        *(short8*)&Bs[sr * LDA + sc] = *(const short8*)&Bt[(size_t)(n0 + sr) * K + k0 + sc];
        __syncthreads();
        short8 a0 = *(short8*)&As[(wm +      lr) * LDA + lk];
        short8 a1 = *(short8*)&As[(wm + 16 + lr) * LDA + lk];
        short8 b0 = *(short8*)&Bs[(wn +      lr) * LDA + lk];
        short8 b1 = *(short8*)&Bs[(wn + 16 + lr) * LDA + lk];
        acc[0][0] = __builtin_amdgcn_mfma_f32_16x16x32_bf16(a0, b0, acc[0][0], 0, 0, 0);
        acc[0][1] = __builtin_amdgcn_mfma_f32_16x16x32_bf16(a0, b1, acc[0][1], 0, 0, 0);
        acc[1][0] = __builtin_amdgcn_mfma_f32_16x16x32_bf16(a1, b0, acc[1][0], 0, 0, 0);
        acc[1][1] = __builtin_amdgcn_mfma_f32_16x16x32_bf16(a1, b1, acc[1][1], 0, 0, 0);
        __syncthreads();
    }
    for (int i = 0; i < 2; i++)
        for (int j = 0; j < 2; j++) {
            int n = n0 + wn + 16 * j + lr;
            float bv = bias[n];
            for (int r = 0; r < 4; r++) {
                int m = m0 + wm + 16 * i + (lane >> 4) * 4 + r;
                Out[(size_t)m * 1024 + n] = acc[i][j][r] + bv;
            }
        }
}

// ---------------------------------------------------------------------------
// Flash attention (causal + key pad mask).
// One q-tile (64 rows) per block (round-3 structure: VGPR ~60, spill-free).
// Round-5 changes:
//  * P aliases the Kt LDS region (safe: extra barrier after all Kt reads)
//      -> LDS 27.6 KB -> 18.4 KB -> 8 blocks/CU = 32 waves/CU static.
//  * LPT dispatch: flat grid, qb = 31 - (blk>>6): heavy blocks first.
//  * Vt XOR key-block swizzle (kept from round 4, measured conflict win).
//  * Q pre-scaled by 1/8 in gemm_qkv epilogue (no per-S multiply here).
// ---------------------------------------------------------------------------
#define DPAD 72   // padded row stride (elems) = 144B

__device__ __forceinline__ float4_ bmfma(short8 a, short8 b, float4_ c) {
    return __builtin_amdgcn_mfma_f32_16x16x32_bf16(a, b, c, 0, 0, 0);
}

__global__ __launch_bounds__(256) void attn_fwd(
    const unsigned short* __restrict__ Q,   // [B][H][T][HD], pre-scaled
    const unsigned short* __restrict__ Kg,
    const unsigned short* __restrict__ Vg,
    const int* __restrict__ pad,            // [B][T]
    unsigned short* __restrict__ Y)         // [B][T][C]
{
    __shared__ unsigned short smem[128 * DPAD];
    unsigned short* Kt = smem;              // [key][d]   64*DPAD (aliased by P)
    unsigned short* Vt = smem + 64 * DPAD;  // [d][key-swizzled]

    int flat = blockIdx.x;          // 0..2047
    int qb = 31 - (flat >> 6);      // heavy-first (LPT)
    int bh = flat & 63;
    int b  = bh >> 4, h = bh & 15;
    const size_t base = (size_t)bh * Tt * HDd;
    int tid  = threadIdx.x;
    int wave = tid >> 6, lane = tid & 63;
    int lr = lane & 15, lg = lane >> 4;
    int q0 = qb * 64 + wave * 16;
    unsigned short* Pw = &Kt[wave * 16 * DPAD];   // per-wave P slice (Kt alias)
    const int* padRow = pad + b * Tt;

    short8 qf0 = *(const short8*)&Q[base + (size_t)(q0 + lr) * HDd + lg * 8];
    short8 qf1 = *(const short8*)&Q[base + (size_t)(q0 + lr) * HDd + 32 + lg * 8];

    float m_i[4], l_i[4];
    float4_ o_acc[4];
    #pragma unroll
    for (int r = 0; r < 4; r++) { m_i[r] = -1e30f; l_i[r] = 0.f; }
    #pragma unroll
    for (int dt = 0; dt < 4; dt++) o_acc[dt] = (float4_){0.f, 0.f, 0.f, 0.f};

    for (int kt = 0; kt <= qb; kt++) {
        int k0 = kt * 64;
        // ---- stage K (as-is) and V (transposed, XOR key-block swizzle) ----
        {
            int r = tid >> 2, cbase = (tid & 3) * 8;
            #pragma unroll
            for (int half = 0; half < 2; half++) {
                int c = cbase + half * 32;
                *(short8*)&Kt[r * DPAD + c] =
                    *(const short8*)&Kg[base + (size_t)(k0 + r) * HDd + c];
                alignas(16) unsigned short tmp[8];
                *(short8*)tmp = *(const short8*)&Vg[base + (size_t)(k0 + r) * HDd + c];
                #pragma unroll
                for (int j = 0; j < 8; j++) {
                    int d = c + j;
                    Vt[d * DPAD + ((((r >> 3) ^ (d >> 3)) << 3) | (r & 7))] = tmp[j];
                }
            }
        }
        __syncthreads();

        // ---- S = Q K^T (Q pre-scaled), causal + pad mask ----
        float4_ s[4];
        #pragma unroll
        for (int nt = 0; nt < 4; nt++) {
            short8 kf0 = *(const short8*)&Kt[(nt * 16 + lr) * DPAD + lg * 8];
            short8 kf1 = *(const short8*)&Kt[(nt * 16 + lr) * DPAD + 32 + lg * 8];
            float4_ a = (float4_){0.f, 0.f, 0.f, 0.f};
            a = bmfma(qf0, kf0, a);
            a = bmfma(qf1, kf1, a);
            s[nt] = a;
        }
        #pragma unroll
        for (int nt = 0; nt < 4; nt++) {
            int key = k0 + nt * 16 + lr;
            bool keep_k = padRow[key] != 0;
            #pragma unroll
            for (int r = 0; r < 4; r++) {
                int qrow = q0 + lg * 4 + r;
                float sv = s[nt][r];
                if (!keep_k || key > qrow) sv = -1e30f;
                s[nt][r] = sv;
            }
        }
        // ---- online softmax ----
        float mn[4], alpha[4];
        #pragma unroll
        for (int r = 0; r < 4; r++) {
            float v = fmaxf(fmaxf(s[0][r], s[1][r]), fmaxf(s[2][r], s[3][r]));
            #pragma unroll
            for (int off = 1; off < 16; off <<= 1)
                v = fmaxf(v, __shfl_xor(v, off, 64));
            float m_new = fmaxf(m_i[r], v);
            alpha[r] = __expf(m_i[r] - m_new);
            mn[r] = m_new;
        }
        float rsum[4] = {0.f, 0.f, 0.f, 0.f};
        #pragma unroll
        for (int nt = 0; nt < 4; nt++)
            #pragma unroll
            for (int r = 0; r < 4; r++) {
                float p = __expf(s[nt][r] - mn[r]);
                s[nt][r] = p;
                rsum[r] += p;
            }
        #pragma unroll
        for (int r = 0; r < 4; r++) {
            float v = rsum[r];
            #pragma unroll
            for (int off = 1; off < 16; off <<= 1)
                v += __shfl_xor(v, off, 64);
            l_i[r] = l_i[r] * alpha[r] + v;
            m_i[r] = mn[r];
        }

        __syncthreads();   // all waves done reading Kt -> safe to write P alias

        // ---- P: C-layout regs -> per-wave LDS slice (Kt alias) ----
        #pragma unroll
        for (int nt = 0; nt < 4; nt++)
            #pragma unroll
            for (int r = 0; r < 4; r++)
                Pw[(lg * 4 + r) * DPAD + nt * 16 + lr] = f2bf(s[nt][r]);
        #pragma unroll
        for (int dt = 0; dt < 4; dt++)
            #pragma unroll
            for (int r = 0; r < 4; r++)
                o_acc[dt][r] *= alpha[r];
        // ---- O += P @ V ----
        short8 pf0 = *(const short8*)&Pw[lr * DPAD + lg * 8];
        short8 pf1 = *(const short8*)&Pw[lr * DPAD + 32 + lg * 8];
        #pragma unroll
        for (int dt = 0; dt < 4; dt++) {
            int d = dt * 16 + lr;
            short8 vf0 = *(const short8*)&Vt[d * DPAD + ((lg ^ (d >> 3)) << 3)];
            short8 vf1 = *(const short8*)&Vt[d * DPAD + (((lg + 4) ^ (d >> 3)) << 3)];
            o_acc[dt] = bmfma(pf0, vf0, o_acc[dt]);
            o_acc[dt] = bmfma(pf1, vf1, o_acc[dt]);
        }
        __syncthreads();   // P consumed + Vt consumed -> safe to restage
    }

    // ---- epilogue: Y[b][t][h*64+d] = O / l  (bf16) ----
    #pragma unroll
    for (int dt = 0; dt < 4; dt++)
        #pragma unroll
        for (int r = 0; r < 4; r++) {
            int qrow = q0 + lg * 4 + r;
            Y[((size_t)b * Tt + qrow) * Cc + h * HDd + dt * 16 + lr] =
                f2bf(o_acc[dt][r] / l_i[r]);
        }
}

// ---------------------------------------------------------------------------
extern "C" void kernel_launch(void* const* d_in, const int* in_sizes, int n_in,
                              void* d_out, int out_size, void* d_ws, size_t ws_size,
                              hipStream_t stream)
{
    const float* x      = (const float*)d_in[0];
    const int*   pad    = (const int*)d_in[1];
    const float* w_attn = (const float*)d_in[2];
    const float* w_proj = (const float*)d_in[3];
    const float* b_proj = (const float*)d_in[4];
    float*       out    = (float*)d_out;

    // workspace carve-up (bf16 elems)
    unsigned short* Wta = (unsigned short*)d_ws;            // 3072*1024
    unsigned short* Wtp = Wta + (size_t)3072 * 1024;        // 1024*1024
    unsigned short* Qb  = Wtp + (size_t)1024 * 1024;
    unsigned short* Kb  = Qb + (size_t)Bb * Hh * Tt * HDd;
    unsigned short* Vb  = Kb + (size_t)Bb * Hh * Tt * HDd;
    unsigned short* Yb  = Vb + (size_t)Bb * Hh * Tt * HDd;

    // 1) transpose+convert weights to bf16 [N][K]
    transpose_f32_bf16<<<dim3(3072 / 32, 1024 / 32), 256, 0, stream>>>(w_attn, Wta, 1024, 3072);
    transpose_f32_bf16<<<dim3(1024 / 32, 1024 / 32), 256, 0, stream>>>(w_proj, Wtp, 1024, 1024);
    // 2) qkv = x @ w_attn, scattered to head-major Q/K/V (bf16, Q pre-scaled)
    gemm_qkv<<<dim3(8192 / BM, 3072 / BN), 256, 0, stream>>>(x, Wta, Qb, Kb, Vb);
    // 3) flash attention (flat grid, heavy-first)
    attn_fwd<<<dim3(2048), 256, 0, stream>>>(Qb, Kb, Vb, pad, Yb);
    // 4) out = y @ w_proj + b_proj (f32 out)
    gemm_proj<<<dim3(8192 / BM, 1024 / BN), 256, 0, stream>>>(Yb, Wtp, b_proj, out);
}

// Round 6
// 331.488 us; speedup vs baseline: 1.7328x; 1.1739x over previous
//
#include <hip/hip_runtime.h>
#include <hip/hip_bf16.h>

// ---------------------------------------------------------------------------
// SelfAttention: y = proj(attn(qkv(x)))   B=4 T=2048 C=1024 H=16 HD=64
// Inputs/outputs are FLOAT32 (per reference); pad_mask is int32.
// Internally: convert to bf16, MFMA 16x16x32 bf16, accumulate f32.
// GEMMs use the m97 structure: 128x128 tile, BK=64, global_load_lds(16B).
// ---------------------------------------------------------------------------

using short8  = __attribute__((ext_vector_type(8))) short;
using float4_ = __attribute__((ext_vector_type(4))) float;

#define Bb   4
#define Tt   2048
#define Cc   1024
#define Hh   16
#define HDd  64

__device__ __forceinline__ float bf2f(unsigned short u) {
    union { float f; unsigned int i; } x; x.i = ((unsigned int)u) << 16; return x.f;
}
__device__ __forceinline__ unsigned short f2bf(float f) {
    union { float f; unsigned int i; } x; x.f = f;
    unsigned int r = x.i + 0x7fff + ((x.i >> 16) & 1);
    return (unsigned short)(r >> 16);
}
__device__ __forceinline__ float4_ bmfma(short8 a, short8 b, float4_ c) {
    return __builtin_amdgcn_mfma_f32_16x16x32_bf16(a, b, c, 0, 0, 0);
}
// async 16B global -> LDS (dest must be wave-uniform base + lane*16)
__device__ __forceinline__ void gl2lds16(const unsigned short* g, unsigned short* l) {
    __builtin_amdgcn_global_load_lds(
        (const __attribute__((address_space(1))) void*)g,
        (__attribute__((address_space(3))) void*)l, 16, 0, 0);
}

// ---------------------------------------------------------------------------
// x f32 -> bf16 (flat)
// ---------------------------------------------------------------------------
__global__ __launch_bounds__(256) void convert_f32_bf16(
    const float* __restrict__ in, unsigned short* __restrict__ out)
{
    size_t idx = ((size_t)blockIdx.x * 256 + threadIdx.x) * 8;
    float4_ f0 = *(const float4_*)&in[idx];
    float4_ f1 = *(const float4_*)&in[idx + 4];
    short8 h;
    h[0] = (short)f2bf(f0[0]); h[1] = (short)f2bf(f0[1]);
    h[2] = (short)f2bf(f0[2]); h[3] = (short)f2bf(f0[3]);
    h[4] = (short)f2bf(f1[0]); h[5] = (short)f2bf(f1[1]);
    h[6] = (short)f2bf(f1[2]); h[7] = (short)f2bf(f1[3]);
    *(short8*)&out[idx] = h;
}

// ---------------------------------------------------------------------------
// Transpose + convert: in f32 [R][Ccols] -> out bf16 [Ccols][R]
// ---------------------------------------------------------------------------
__global__ __launch_bounds__(256) void transpose_f32_bf16(
    const float* __restrict__ in, unsigned short* __restrict__ out,
    int R, int Ccols)
{
    __shared__ unsigned short tile[32][33];
    int c0 = blockIdx.x * 32, r0 = blockIdx.y * 32;
    int tx = threadIdx.x & 31, ty = threadIdx.x >> 5;   // ty 0..7
    for (int o = 0; o < 32; o += 8)
        tile[ty + o][tx] = f2bf(in[(size_t)(r0 + ty + o) * Ccols + c0 + tx]);
    __syncthreads();
    for (int o = 0; o < 32; o += 8)
        out[(size_t)(c0 + ty + o) * R + r0 + tx] = tile[tx][ty + o];
}

// ---------------------------------------------------------------------------
// m97-style GEMM main loop: C = A[M][K](bf16) * Bt[N][K](bf16)^T
// 128x128 block tile, BK=64, 4 waves each computing 64x64 via 4x4 MFMA.
// LDS unpadded [row][k] (global_load_lds needs lane-contiguous dest).
// ---------------------------------------------------------------------------
#define GBK 64

__device__ __forceinline__ void gemm128_main(
    const unsigned short* __restrict__ A, const unsigned short* __restrict__ Bt,
    int K, int m0, int n0,
    unsigned short* As, unsigned short* Bs, float4_ acc[4][4])
{
    int tid  = threadIdx.x;
    int wave = tid >> 6, lane = tid & 63;
    int wm = (wave >> 1) * 64, wn = (wave & 1) * 64;
    int lr = lane & 15, lg = lane >> 4;
    int srow = tid >> 3;            // 0..31
    int scol = (tid & 7) * 8;       // 0..56

    for (int k0 = 0; k0 < K; k0 += GBK) {
        #pragma unroll
        for (int j = 0; j < 4; j++) {
            int row = j * 32 + srow;
            gl2lds16(&A [(size_t)(m0 + row) * K + k0 + scol], &As[row * GBK + scol]);
            gl2lds16(&Bt[(size_t)(n0 + row) * K + k0 + scol], &Bs[row * GBK + scol]);
        }
        __syncthreads();
        #pragma unroll
        for (int ks = 0; ks < GBK; ks += 32) {
            short8 af[4], bf[4];
            #pragma unroll
            for (int i = 0; i < 4; i++) {
                af[i] = *(const short8*)&As[(wm + i * 16 + lr) * GBK + ks + lg * 8];
                bf[i] = *(const short8*)&Bs[(wn + i * 16 + lr) * GBK + ks + lg * 8];
            }
            #pragma unroll
            for (int i = 0; i < 4; i++)
                #pragma unroll
                for (int j = 0; j < 4; j++)
                    acc[i][j] = bmfma(af[i], bf[j], acc[i][j]);
        }
        __syncthreads();
    }
}

__global__ __launch_bounds__(256) void gemm_qkv(
    const unsigned short* __restrict__ A,   // x: [8192][1024] bf16
    const unsigned short* __restrict__ Bt,  // w_attn^T: [3072][1024] bf16
    unsigned short* __restrict__ Q,         // [B][H][T][HD] bf16 (pre-scaled 1/8)
    unsigned short* __restrict__ Ko,
    unsigned short* __restrict__ V)
{
    __shared__ unsigned short As[128 * GBK];
    __shared__ unsigned short Bs[128 * GBK];
    int m0 = blockIdx.x * 128, n0 = blockIdx.y * 128;
    float4_ acc[4][4] = {};
    gemm128_main(A, Bt, 1024, m0, n0, As, Bs, acc);

    int lane = threadIdx.x & 63, wave = threadIdx.x >> 6;
    int wm = (wave >> 1) * 64, wn = (wave & 1) * 64;
    int lr = lane & 15, lg = lane >> 4;
    #pragma unroll
    for (int i = 0; i < 4; i++)
        #pragma unroll
        for (int j = 0; j < 4; j++) {
            int n = n0 + wn + 16 * j + lr;
            int which = n >> 10;
            int c = n & 1023;
            int h = c >> 6, d = c & 63;
            unsigned short* dst = (which == 0) ? Q : ((which == 1) ? Ko : V);
            float sc2 = (which == 0) ? 0.125f : 1.0f;   // fold 1/sqrt(64) into Q
            #pragma unroll
            for (int r = 0; r < 4; r++) {
                int m = m0 + wm + 16 * i + lg * 4 + r;
                int b = m >> 11, t = m & 2047;
                dst[(((size_t)(b * Hh + h) * Tt) + t) * HDd + d] = f2bf(acc[i][j][r] * sc2);
            }
        }
}

__global__ __launch_bounds__(256) void gemm_proj(
    const unsigned short* __restrict__ A,   // y: [8192][1024] bf16
    const unsigned short* __restrict__ Bt,  // w_proj^T: [1024][1024] bf16
    const float* __restrict__ bias,         // [1024] f32
    float* __restrict__ Out)                // [8192][1024] f32
{
    __shared__ unsigned short As[128 * GBK];
    __shared__ unsigned short Bs[128 * GBK];
    int m0 = blockIdx.x * 128, n0 = blockIdx.y * 128;
    float4_ acc[4][4] = {};
    gemm128_main(A, Bt, 1024, m0, n0, As, Bs, acc);

    int lane = threadIdx.x & 63, wave = threadIdx.x >> 6;
    int wm = (wave >> 1) * 64, wn = (wave & 1) * 64;
    int lr = lane & 15, lg = lane >> 4;
    #pragma unroll
    for (int i = 0; i < 4; i++)
        #pragma unroll
        for (int j = 0; j < 4; j++) {
            int n = n0 + wn + 16 * j + lr;
            float bv = bias[n];
            #pragma unroll
            for (int r = 0; r < 4; r++) {
                int m = m0 + wm + 16 * i + lg * 4 + r;
                Out[(size_t)m * 1024 + n] = acc[i][j][r] + bv;
            }
        }
}

// ---------------------------------------------------------------------------
// Flash attention (causal + key pad mask) — unchanged from round 5.
// ---------------------------------------------------------------------------
#define DPAD 72   // padded row stride (elems) = 144B

__global__ __launch_bounds__(256) void attn_fwd(
    const unsigned short* __restrict__ Q,   // [B][H][T][HD], pre-scaled
    const unsigned short* __restrict__ Kg,
    const unsigned short* __restrict__ Vg,
    const int* __restrict__ pad,            // [B][T]
    unsigned short* __restrict__ Y)         // [B][T][C]
{
    __shared__ unsigned short smem[128 * DPAD];
    unsigned short* Kt = smem;              // [key][d]   64*DPAD (aliased by P)
    unsigned short* Vt = smem + 64 * DPAD;  // [d][key-swizzled]

    int flat = blockIdx.x;          // 0..2047
    int qb = 31 - (flat >> 6);      // heavy-first (LPT)
    int bh = flat & 63;
    int b  = bh >> 4, h = bh & 15;
    const size_t base = (size_t)bh * Tt * HDd;
    int tid  = threadIdx.x;
    int wave = tid >> 6, lane = tid & 63;
    int lr = lane & 15, lg = lane >> 4;
    int q0 = qb * 64 + wave * 16;
    unsigned short* Pw = &Kt[wave * 16 * DPAD];   // per-wave P slice (Kt alias)
    const int* padRow = pad + b * Tt;

    short8 qf0 = *(const short8*)&Q[base + (size_t)(q0 + lr) * HDd + lg * 8];
    short8 qf1 = *(const short8*)&Q[base + (size_t)(q0 + lr) * HDd + 32 + lg * 8];

    float m_i[4], l_i[4];
    float4_ o_acc[4];
    #pragma unroll
    for (int r = 0; r < 4; r++) { m_i[r] = -1e30f; l_i[r] = 0.f; }
    #pragma unroll
    for (int dt = 0; dt < 4; dt++) o_acc[dt] = (float4_){0.f, 0.f, 0.f, 0.f};

    for (int kt = 0; kt <= qb; kt++) {
        int k0 = kt * 64;
        // ---- stage K (as-is) and V (transposed, XOR key-block swizzle) ----
        {
            int r = tid >> 2, cbase = (tid & 3) * 8;
            #pragma unroll
            for (int half = 0; half < 2; half++) {
                int c = cbase + half * 32;
                *(short8*)&Kt[r * DPAD + c] =
                    *(const short8*)&Kg[base + (size_t)(k0 + r) * HDd + c];
                alignas(16) unsigned short tmp[8];
                *(short8*)tmp = *(const short8*)&Vg[base + (size_t)(k0 + r) * HDd + c];
                #pragma unroll
                for (int j = 0; j < 8; j++) {
                    int d = c + j;
                    Vt[d * DPAD + ((((r >> 3) ^ (d >> 3)) << 3) | (r & 7))] = tmp[j];
                }
            }
        }
        __syncthreads();

        // ---- S = Q K^T (Q pre-scaled), causal + pad mask ----
        float4_ s[4];
        #pragma unroll
        for (int nt = 0; nt < 4; nt++) {
            short8 kf0 = *(const short8*)&Kt[(nt * 16 + lr) * DPAD + lg * 8];
            short8 kf1 = *(const short8*)&Kt[(nt * 16 + lr) * DPAD + 32 + lg * 8];
            float4_ a = (float4_){0.f, 0.f, 0.f, 0.f};
            a = bmfma(qf0, kf0, a);
            a = bmfma(qf1, kf1, a);
            s[nt] = a;
        }
        #pragma unroll
        for (int nt = 0; nt < 4; nt++) {
            int key = k0 + nt * 16 + lr;
            bool keep_k = padRow[key] != 0;
            #pragma unroll
            for (int r = 0; r < 4; r++) {
                int qrow = q0 + lg * 4 + r;
                float sv = s[nt][r];
                if (!keep_k || key > qrow) sv = -1e30f;
                s[nt][r] = sv;
            }
        }
        // ---- online softmax ----
        float mn[4], alpha[4];
        #pragma unroll
        for (int r = 0; r < 4; r++) {
            float v = fmaxf(fmaxf(s[0][r], s[1][r]), fmaxf(s[2][r], s[3][r]));
            #pragma unroll
            for (int off = 1; off < 16; off <<= 1)
                v = fmaxf(v, __shfl_xor(v, off, 64));
            float m_new = fmaxf(m_i[r], v);
            alpha[r] = __expf(m_i[r] - m_new);
            mn[r] = m_new;
        }
        float rsum[4] = {0.f, 0.f, 0.f, 0.f};
        #pragma unroll
        for (int nt = 0; nt < 4; nt++)
            #pragma unroll
            for (int r = 0; r < 4; r++) {
                float p = __expf(s[nt][r] - mn[r]);
                s[nt][r] = p;
                rsum[r] += p;
            }
        #pragma unroll
        for (int r = 0; r < 4; r++) {
            float v = rsum[r];
            #pragma unroll
            for (int off = 1; off < 16; off <<= 1)
                v += __shfl_xor(v, off, 64);
            l_i[r] = l_i[r] * alpha[r] + v;
            m_i[r] = mn[r];
        }

        __syncthreads();   // all waves done reading Kt -> safe to write P alias

        // ---- P: C-layout regs -> per-wave LDS slice (Kt alias) ----
        #pragma unroll
        for (int nt = 0; nt < 4; nt++)
            #pragma unroll
            for (int r = 0; r < 4; r++)
                Pw[(lg * 4 + r) * DPAD + nt * 16 + lr] = f2bf(s[nt][r]);
        #pragma unroll
        for (int dt = 0; dt < 4; dt++)
            #pragma unroll
            for (int r = 0; r < 4; r++)
                o_acc[dt][r] *= alpha[r];
        // ---- O += P @ V ----
        short8 pf0 = *(const short8*)&Pw[lr * DPAD + lg * 8];
        short8 pf1 = *(const short8*)&Pw[lr * DPAD + 32 + lg * 8];
        #pragma unroll
        for (int dt = 0; dt < 4; dt++) {
            int d = dt * 16 + lr;
            short8 vf0 = *(const short8*)&Vt[d * DPAD + ((lg ^ (d >> 3)) << 3)];
            short8 vf1 = *(const short8*)&Vt[d * DPAD + (((lg + 4) ^ (d >> 3)) << 3)];
            o_acc[dt] = bmfma(pf0, vf0, o_acc[dt]);
            o_acc[dt] = bmfma(pf1, vf1, o_acc[dt]);
        }
        __syncthreads();   // P consumed + Vt consumed -> safe to restage
    }

    // ---- epilogue: Y[b][t][h*64+d] = O / l  (bf16) ----
    #pragma unroll
    for (int dt = 0; dt < 4; dt++)
        #pragma unroll
        for (int r = 0; r < 4; r++) {
            int qrow = q0 + lg * 4 + r;
            Y[((size_t)b * Tt + qrow) * Cc + h * HDd + dt * 16 + lr] =
                f2bf(o_acc[dt][r] / l_i[r]);
        }
}

// ---------------------------------------------------------------------------
extern "C" void kernel_launch(void* const* d_in, const int* in_sizes, int n_in,
                              void* d_out, int out_size, void* d_ws, size_t ws_size,
                              hipStream_t stream)
{
    const float* x      = (const float*)d_in[0];
    const int*   pad    = (const int*)d_in[1];
    const float* w_attn = (const float*)d_in[2];
    const float* w_proj = (const float*)d_in[3];
    const float* b_proj = (const float*)d_in[4];
    float*       out    = (float*)d_out;

    // workspace carve-up (bf16 elems). Yb aliases Xb (x-bf16 dead after qkv).
    unsigned short* Wta = (unsigned short*)d_ws;            // 3072*1024
    unsigned short* Wtp = Wta + (size_t)3072 * 1024;        // 1024*1024
    unsigned short* Xb  = Wtp + (size_t)1024 * 1024;        // 8192*1024
    unsigned short* Yb  = Xb;                               // alias
    unsigned short* Qb  = Xb + (size_t)8192 * 1024;
    unsigned short* Kb  = Qb + (size_t)Bb * Hh * Tt * HDd;
    unsigned short* Vb  = Kb + (size_t)Bb * Hh * Tt * HDd;

    // 0) x f32 -> bf16
    convert_f32_bf16<<<dim3(4096), 256, 0, stream>>>(x, Xb);
    // 1) transpose+convert weights to bf16 [N][K]
    transpose_f32_bf16<<<dim3(3072 / 32, 1024 / 32), 256, 0, stream>>>(w_attn, Wta, 1024, 3072);
    transpose_f32_bf16<<<dim3(1024 / 32, 1024 / 32), 256, 0, stream>>>(w_proj, Wtp, 1024, 1024);
    // 2) qkv = x @ w_attn, scattered to head-major Q/K/V (bf16, Q pre-scaled)
    gemm_qkv<<<dim3(8192 / 128, 3072 / 128), 256, 0, stream>>>(Xb, Wta, Qb, Kb, Vb);
    // 3) flash attention (flat grid, heavy-first)
    attn_fwd<<<dim3(2048), 256, 0, stream>>>(Qb, Kb, Vb, pad, Yb);
    // 4) out = y @ w_proj + b_proj (f32 out)
    gemm_proj<<<dim3(8192 / 128, 1024 / 128), 256, 0, stream>>>(Yb, Wtp, b_proj, out);
}